// Round 1
// baseline (5266.092 us; speedup 1.0000x reference)
//
#include <hip/hip_runtime.h>
#include <cstddef>

#define B_  64
#define T_  256
#define I_  256
#define H_  1024
#define C_  1000

typedef _Float16 f16;
typedef __attribute__((ext_vector_type(8))) _Float16 f16x8;
typedef __attribute__((ext_vector_type(4))) float f32x4;

__device__ __forceinline__ float sigmoid_(float v) { return 1.0f / (1.0f + __expf(-v)); }
__device__ __forceinline__ float tanh_(float v) {
  float e = __expf(-2.0f * fabsf(v));
  float t = (1.0f - e) / (1.0f + e);
  return copysignf(t, v);
}

// two-level grid barrier: 8 bucket counters + 1 master, monotonic (no reset).
__device__ __forceinline__ void grid_barrier(unsigned* sync, int bid, int phase) {
  __syncthreads();
  if (threadIdx.x == 0) {
    unsigned* master = sync;
    unsigned* bucket = sync + 32 * (1 + (bid & 7));   // 128B-spaced lines
    __hip_atomic_fetch_add(bucket, 1u, __ATOMIC_RELEASE, __HIP_MEMORY_SCOPE_AGENT);
    if (bid < 8) {
      const unsigned bt = 32u * (unsigned)(phase + 1);
      int guard = 0;
      while (__hip_atomic_load(bucket, __ATOMIC_RELAXED, __HIP_MEMORY_SCOPE_AGENT) < bt) {
        __builtin_amdgcn_s_sleep(2);
        if (++guard > (1 << 15)) break;   // safety bail (never hit if co-resident)
      }
      __builtin_amdgcn_fence(__ATOMIC_ACQUIRE, "agent");
      __hip_atomic_fetch_add(master, 1u, __ATOMIC_RELEASE, __HIP_MEMORY_SCOPE_AGENT);
    }
    const unsigned mt = 8u * (unsigned)(phase + 1);
    int guard2 = 0;
    while (__hip_atomic_load(master, __ATOMIC_RELAXED, __HIP_MEMORY_SCOPE_AGENT) < mt) {
      __builtin_amdgcn_s_sleep(2);
      if (++guard2 > (1 << 15)) break;
    }
    __builtin_amdgcn_fence(__ATOMIC_ACQUIRE, "agent");
  }
  __syncthreads();
}

// One block = one layer-role, 32 batch rows (mgroup), 16 hidden units x 4 gates (64 cols).
// Weights live in VGPRs (f16 MFMA B-frags). K is split across the 4 waves; partial z
// reduced via LDS; gates fused; h published fp16 to global double buffers.
template<bool IS_L1>
__device__ __forceinline__ void role_main(
    const float* __restrict__ x,
    const float* __restrict__ Wx, const float* __restrict__ Wh,
    const float* __restrict__ bias,
    f16* __restrict__ h0buf, f16* __restrict__ h1buf,
    unsigned* sync, int bid,
    float* zbAll, float* cLDS, float* biasLDS)
{
  constexpr int KTOT = IS_L1 ? 64 : 40;   // k-tiles of 32 (L0: 8 x-tiles + 32 h-tiles)
  constexpr int NKT  = KTOT / 4;          // per-wave k-tiles
  constexpr int KX   = IS_L1 ? 1024 : 256;

  const int tid  = threadIdx.x;
  const int wv   = tid >> 6;
  const int lane = tid & 63;
  const int c16  = lane & 15;
  const int quad = lane >> 4;
  const int rr7  = bid & 127;
  const int mgroup  = rr7 & 1;
  const int ubase   = (rr7 >> 1) * 16;    // 16 hidden units per block
  const int rowbase = mgroup * 32;

  if (tid < 64) biasLDS[tid] = bias[(size_t)(tid >> 4) * H_ + ubase + (tid & 15)];
  for (int i = tid; i < 512; i += 256) cLDS[i] = 0.0f;

  // ---- weight prologue: coalesced global fp32 -> LDS panel -> f16 B-frags in VGPRs
  f16x8 Wreg[4][NKT];
  {
    f16* zpan = (f16*)(zbAll + wv * 2048);   // private 4KB panel per wave
    const int ktb = wv * NKT;
#pragma unroll
    for (int ii = 0; ii < NKT; ++ii) {
      const int kt = ktb + ii;
#pragma unroll
      for (int rw = 0; rw < 32; ++rw) {
        const int k = kt * 32 + rw;
        float wval;
        if (k < KX) wval = Wx[((size_t)quad * KX + k) * H_ + ubase + c16];
        else        wval = Wh[((size_t)quad * H_ + (k - KX)) * H_ + ubase + c16];
        zpan[rw * 64 + lane] = (f16)wval;     // panel[k-in-tile][col], col=g*16+u
      }
#pragma unroll
      for (int nt = 0; nt < 4; ++nt) {
        f16x8 f;
#pragma unroll
        for (int j = 0; j < 8; ++j)
          f[j] = zpan[(quad * 8 + j) * 64 + nt * 16 + c16];  // B[n=lane&15][k=quad*8+j]
        Wreg[nt][ii] = f;
      }
    }
  }
  __syncthreads();

  const int ktbase = wv * NKT;
  const int row0 = rowbase + c16;

#pragma unroll 1
  for (int p = 0; p <= T_; ++p) {
    const bool active = IS_L1 ? (p >= 1) : (p < T_);
    if (active) {
      const f16* __restrict__ hA = h0buf + ((p + 1) & 1) * (B_ * H_);  // h0[p-1]
      const f16* __restrict__ hB = IS_L1 ? (h1buf + (p & 1) * (B_ * H_)) : (const f16*)nullptr; // h1[p-2]
      f16* __restrict__ hdst = IS_L1 ? (h1buf + ((p + 1) & 1) * (B_ * H_))
                                     : (h0buf + (p & 1) * (B_ * H_));

      f16x8 Abuf[4][2];
      auto loadA = [&](int ii, int slot) {
        const int kt = ktbase + ii;
        const int k  = kt * 32 + quad * 8;
#pragma unroll
        for (int mt = 0; mt < 2; ++mt) {
          const int row = row0 + mt * 16;
          if (!IS_L1 && kt < 8) {       // x-part: fp32 load + on-the-fly f16 cvt
            const float4* xp = (const float4*)(x + ((size_t)row * T_ + p) * I_ + k);
            const float4 xa = xp[0], xb = xp[1];
            f16x8 f;
            f[0] = (f16)xa.x; f[1] = (f16)xa.y; f[2] = (f16)xa.z; f[3] = (f16)xa.w;
            f[4] = (f16)xb.x; f[5] = (f16)xb.y; f[6] = (f16)xb.z; f[7] = (f16)xb.w;
            Abuf[slot][mt] = f;
          } else if (IS_L1 && k >= 1024) {
            Abuf[slot][mt] = *(const f16x8*)(hB + (size_t)row * H_ + (k - 1024));
          } else {
            const int kk = IS_L1 ? k : (k - 256);
            Abuf[slot][mt] = *(const f16x8*)(hA + (size_t)row * H_ + kk);
          }
        }
      };

      f32x4 acc[2][4];
#pragma unroll
      for (int mt = 0; mt < 2; ++mt)
#pragma unroll
        for (int nt = 0; nt < 4; ++nt)
          acc[mt][nt] = (f32x4)0.0f;

      loadA(0, 0); loadA(1, 1); loadA(2, 2); loadA(3, 3);  // prefetch ring depth 4
#pragma unroll
      for (int i = 0; i < NKT; ++i) {
        const f16x8 a0 = Abuf[i & 3][0];
        const f16x8 a1 = Abuf[i & 3][1];
        if (i + 4 < NKT) loadA(i + 4, (i + 4) & 3);
#pragma unroll
        for (int nt = 0; nt < 4; ++nt) {
          acc[0][nt] = __builtin_amdgcn_mfma_f32_16x16x32_f16(a0, Wreg[nt][i], acc[0][nt], 0, 0, 0);
          acc[1][nt] = __builtin_amdgcn_mfma_f32_16x16x32_f16(a1, Wreg[nt][i], acc[1][nt], 0, 0, 0);
        }
      }

      // partial z -> LDS (C/D layout: col=lane&15, row=quad*4+e)
      float* zw = zbAll + wv * 2048;
#pragma unroll
      for (int mt = 0; mt < 2; ++mt)
#pragma unroll
        for (int nt = 0; nt < 4; ++nt)
#pragma unroll
          for (int e = 0; e < 4; ++e)
            zw[(mt * 4 + nt) * 256 + (quad * 4 + e) * 16 + c16] = acc[mt][nt][e];

      __syncthreads();

      // stage 1: reduce 4 wave-partials + bias (in place into wave-0 region)
      {
        const int base = tid * 8;
        f32x4 s0 = (f32x4)0.0f, s1 = (f32x4)0.0f;
#pragma unroll
        for (int w2 = 0; w2 < 4; ++w2) {
          const f32x4* pz = (const f32x4*)(zbAll + w2 * 2048 + base);
          s0 += pz[0];
          s1 += pz[1];
        }
        const int nt   = (base >> 8) & 3;
        const int col0 = nt * 16 + (base & 15);
        const f32x4* bv = (const f32x4*)(biasLDS + col0);
        s0 += bv[0];
        s1 += bv[1];
        f32x4* oz = (f32x4*)(zbAll + base);
        oz[0] = s0;
        oz[1] = s1;
      }
      __syncthreads();

      // stage 2: fused gates; c stays in LDS, h published fp16
#pragma unroll
      for (int pp = 0; pp < 2; ++pp) {
        const int pr  = tid + pp * 256;      // (row, unit) pair: 32 rows x 16 units
        const int row = pr >> 4, u = pr & 15;
        const int mt  = row >> 4, r16 = row & 15;
        const float z0 = zbAll[(mt * 4 + 0) * 256 + r16 * 16 + u];
        const float z1 = zbAll[(mt * 4 + 1) * 256 + r16 * 16 + u];
        const float z2 = zbAll[(mt * 4 + 2) * 256 + r16 * 16 + u];
        const float z3 = zbAll[(mt * 4 + 3) * 256 + r16 * 16 + u];
        const float cv = cLDS[pr];
        const float gt = tanh_(z0);
        const float iv = sigmoid_(z1);
        const float fv = sigmoid_(z2);
        const float ov = sigmoid_(z3);
        const float cn = gt * iv + cv * fv;
        cLDS[pr] = cn;
        const float hn = tanh_(cn) * ov;
        hdst[(size_t)(rowbase + row) * H_ + ubase + u] = (f16)hn;
      }
    }
    grid_barrier(sync, bid, p);
  }
}

__global__ __launch_bounds__(256, 1)
void lstm_persistent(const float* __restrict__ x,
                     const float* __restrict__ W0x, const float* __restrict__ W0h, const float* __restrict__ b0,
                     const float* __restrict__ W1x, const float* __restrict__ W1h, const float* __restrict__ b1,
                     f16* h0buf, f16* h1buf, unsigned* sync)
{
  __shared__ float zbAll[8192];    // 32KB: wave panels / partial z / final z
  __shared__ float cLDS[512];      // cell state, 32 rows x 16 units
  __shared__ float biasLDS[64];
  const int bid = blockIdx.x;
  if (bid >= 128)
    role_main<true >(x, W1x, W1h, b1, h0buf, h1buf, sync, bid, zbAll, cLDS, biasLDS);
  else
    role_main<false>(x, W0x, W0h, b0, h0buf, h1buf, sync, bid, zbAll, cLDS, biasLDS);
}

// out[b][c] = h1_final[b][:] . Wo[:][c] + bo[c]   (fp32 vector math)
__global__ void out_gemm(const f16* __restrict__ h1,
                         const float* __restrict__ Wo, const float* __restrict__ bo,
                         float* __restrict__ out)
{
  __shared__ float ht[1024][8];   // [k][row-in-group], padded to 8 for b128 broadcast
  const int tid = threadIdx.x;    // 128 threads
  const int b0r = blockIdx.y * 4;
  for (int i = tid; i < 4096; i += 128) {
    const int rr = i >> 10, k = i & 1023;
    ht[k][rr] = (float)h1[(size_t)(b0r + rr) * H_ + k];
  }
  __syncthreads();
  const int c = blockIdx.x * 125 + tid;
  if (tid < 125) {
    float a0 = 0.f, a1 = 0.f, a2 = 0.f, a3 = 0.f;
#pragma unroll 4
    for (int k = 0; k < 1024; ++k) {
      const float w = Wo[(size_t)k * C_ + c];
      a0 += ht[k][0] * w;
      a1 += ht[k][1] * w;
      a2 += ht[k][2] * w;
      a3 += ht[k][3] * w;
    }
    const float bb = bo[c];
    out[(size_t)(b0r + 0) * C_ + c] = a0 + bb;
    out[(size_t)(b0r + 1) * C_ + c] = a1 + bb;
    out[(size_t)(b0r + 2) * C_ + c] = a2 + bb;
    out[(size_t)(b0r + 3) * C_ + c] = a3 + bb;
  }
}

extern "C" void kernel_launch(void* const* d_in, const int* in_sizes, int n_in,
                              void* d_out, int out_size, void* d_ws, size_t ws_size,
                              hipStream_t stream)
{
  const float* x   = (const float*)d_in[0];
  const float* W0x = (const float*)d_in[1];
  const float* W0h = (const float*)d_in[2];
  const float* b0  = (const float*)d_in[3];
  const float* W1x = (const float*)d_in[4];
  const float* W1h = (const float*)d_in[5];
  const float* b1  = (const float*)d_in[6];
  const float* Wo  = (const float*)d_in[7];
  const float* bo  = (const float*)d_in[8];

  unsigned* sync = (unsigned*)d_ws;                      // barrier counters (4KB)
  f16* h0buf = (f16*)((char*)d_ws + 4096);               // [2][64][1024] f16
  f16* h1buf = h0buf + 2 * (B_ * H_);                    // [2][64][1024] f16

  hipMemsetAsync(d_ws, 0, 4096 + (size_t)4 * B_ * H_ * sizeof(f16), stream);

  hipLaunchKernelGGL(lstm_persistent, dim3(256), dim3(256), 0, stream,
                     x, W0x, W0h, b0, W1x, W1h, b1, h0buf, h1buf, sync);

  // final h1 is at parity (T-1)&1 = 1
  hipLaunchKernelGGL(out_gemm, dim3(8, 16), dim3(128), 0, stream,
                     h1buf + (B_ * H_), Wo, bo, (float*)d_out);
}

// Round 2
// 5176.884 us; speedup vs baseline: 1.0172x; 1.0172x over previous
//
#include <hip/hip_runtime.h>
#include <cstddef>

#define B_  64
#define T_  256
#define I_  256
#define H_  1024
#define C_  1000

typedef _Float16 f16;
typedef __attribute__((ext_vector_type(8))) _Float16 f16x8;
typedef __attribute__((ext_vector_type(4))) float f32x4;

__device__ __forceinline__ float sigmoid_(float v) { return 1.0f / (1.0f + __expf(-v)); }
__device__ __forceinline__ float tanh_(float v) {
  float e = __expf(-2.0f * fabsf(v));
  float t = (1.0f - e) / (1.0f + e);
  return copysignf(t, v);
}

// h store: agent-scope relaxed atomic store -> global_store_dword sc0 sc1
// (write-through to the coherence point; leaves NO dirty L2 lines, so no
// buffer_wbl2 is ever needed -> h never round-trips through HBM).
__device__ __forceinline__ void storeH2(f16* p, float a, float b) {
  union { f16 h[2]; unsigned u; } pk;
  pk.h[0] = (f16)a; pk.h[1] = (f16)b;
  __hip_atomic_store((unsigned*)p, pk.u, __ATOMIC_RELAXED, __HIP_MEMORY_SCOPE_AGENT);
}

// Two-level barrier, all RELAXED atomics. Release ordering comes free from
// __syncthreads (compiler drains vmcnt(0) before s_barrier, so all waves'
// write-through h stores have reached the coherence point before the flag add).
// Acquire side: ONE agent acquire fence (L1+L2 invalidate, nothing dirty to
// write back) so the subsequent plain cached h loads refill from fresh data.
__device__ __forceinline__ void grid_barrier(unsigned* sync, int bid, int phase) {
  __syncthreads();
  if (threadIdx.x == 0) {
    unsigned* master = sync;
    unsigned* bucket = sync + 32 * (1 + (bid & 7));   // 128B-spaced lines
    __hip_atomic_fetch_add(bucket, 1u, __ATOMIC_RELAXED, __HIP_MEMORY_SCOPE_AGENT);
    if (bid < 8) {
      const unsigned bt = 32u * (unsigned)(phase + 1);
      int g = 0;
      while (__hip_atomic_load(bucket, __ATOMIC_RELAXED, __HIP_MEMORY_SCOPE_AGENT) < bt) {
        __builtin_amdgcn_s_sleep(1);
        if (++g > (1 << 16)) break;
      }
      __hip_atomic_fetch_add(master, 1u, __ATOMIC_RELAXED, __HIP_MEMORY_SCOPE_AGENT);
    }
    const unsigned mt = 8u * (unsigned)(phase + 1);
    int g2 = 0;
    while (__hip_atomic_load(master, __ATOMIC_RELAXED, __HIP_MEMORY_SCOPE_AGENT) < mt) {
      __builtin_amdgcn_s_sleep(1);
      if (++g2 > (1 << 16)) break;
    }
    __builtin_amdgcn_fence(__ATOMIC_ACQUIRE, "agent");  // invalidate only
  }
  __syncthreads();
}

// One block = 512 threads = 8 waves = (K-split 4) x (N-split 2).
// Block tile: 32 batch rows x 64 gate-cols (4 gates x 16 units).
// Per-wave weights: K/4 x 32 cols f16 = 128 VGPRs -> 2 waves/SIMD.
template<bool IS_L1>
__device__ __forceinline__ void role_main(
    const f16* __restrict__ x16,
    const float* __restrict__ Wx, const float* __restrict__ Wh,
    const float* __restrict__ bias,
    f16* __restrict__ h0buf, f16* __restrict__ h1buf,
    unsigned* sync, int bid,
    float* zbAll, float* cLDS, float* biasLDS)
{
  constexpr int KTOT = IS_L1 ? 64 : 40;   // k-tiles of 32 (L0: 8 x-tiles + 32 h-tiles)
  constexpr int NKT  = KTOT / 4;          // per-wave k-tiles (K-split over kq)
  constexpr int KX   = IS_L1 ? 1024 : 256;

  const int tid  = threadIdx.x;
  const int wv   = tid >> 6;          // 0..7
  const int nh   = wv >> 2;           // col-half (32 cols each)
  const int kq   = wv & 3;            // K quarter
  const int lane = tid & 63;
  const int c16  = lane & 15;
  const int quad = lane >> 4;
  const int rr7  = bid & 127;
  const int mgroup  = rr7 & 1;
  const int ubase   = (rr7 >> 1) * 16;
  const int rowbase = mgroup * 32;

  if (tid < 64) biasLDS[tid] = bias[(size_t)(tid >> 4) * H_ + ubase + (tid & 15)];
  if (tid < 512) cLDS[tid] = 0.0f;

  // ---- weight prologue: global fp32 -> per-wave LDS panel -> f16 B-frags in regs
  f16x8 Wreg[2][NKT];
  {
    f16* zpan = (f16*)zbAll + wv * 1024;   // private 2KB panel per wave
#pragma unroll 1
    for (int ii = 0; ii < NKT; ++ii) {
      const int kt = kq * NKT + ii;
#pragma unroll
      for (int rw = 0; rw < 16; ++rw) {
        const int krow  = rw * 2 + (lane >> 5);
        const int col32 = lane & 31;
        const int g = nh * 2 + (col32 >> 4);
        const int u = col32 & 15;
        const int k = kt * 32 + krow;
        float wval = (k < KX) ? Wx[((size_t)g * KX + k) * H_ + ubase + u]
                              : Wh[((size_t)g * H_ + (k - KX)) * H_ + ubase + u];
        zpan[krow * 32 + col32] = (f16)wval;
      }
#pragma unroll
      for (int nt = 0; nt < 2; ++nt) {
        f16x8 f;
#pragma unroll
        for (int j = 0; j < 8; ++j)
          f[j] = zpan[(quad * 8 + j) * 32 + nt * 16 + c16];  // B[n=lane&15][k=quad*8+j]
        Wreg[nt][ii] = f;
      }
    }
  }
  __syncthreads();

  const int ktbase = kq * NKT;
  const int row0 = rowbase + c16;

#pragma unroll 1
  for (int p = 0; p <= T_; ++p) {
    const bool active = IS_L1 ? (p >= 1) : (p < T_);
    if (active) {
      const f16* __restrict__ hA = h0buf + ((p + 1) & 1) * (B_ * H_);  // h0[p-1]
      const f16* __restrict__ hB = IS_L1 ? (h1buf + (p & 1) * (B_ * H_)) : (const f16*)nullptr;
      f16* __restrict__ hdst = IS_L1 ? (h1buf + ((p + 1) & 1) * (B_ * H_))
                                     : (h0buf + (p & 1) * (B_ * H_));

      f16x8 Abuf[6][2];
      auto loadA = [&](int ii, int slot) {
        const int kt = ktbase + ii;
        const int k  = kt * 32 + quad * 8;
#pragma unroll
        for (int mt2 = 0; mt2 < 2; ++mt2) {
          const int row = row0 + mt2 * 16;
          if (!IS_L1 && k < 256) {          // x-part: pre-converted f16, cached
            Abuf[slot][mt2] = *(const f16x8*)(x16 + ((size_t)row * T_ + p) * I_ + k);
          } else if (IS_L1 && k >= 1024) {
            Abuf[slot][mt2] = *(const f16x8*)(hB + (size_t)row * H_ + (k - 1024));
          } else {
            const int kk = IS_L1 ? k : (k - 256);
            Abuf[slot][mt2] = *(const f16x8*)(hA + (size_t)row * H_ + kk);
          }
        }
      };

      f32x4 acc[2][2];
#pragma unroll
      for (int mt2 = 0; mt2 < 2; ++mt2)
#pragma unroll
        for (int nt = 0; nt < 2; ++nt)
          acc[mt2][nt] = (f32x4)0.0f;

      loadA(0, 0); loadA(1, 1); loadA(2, 2);
      loadA(3, 3); loadA(4, 4); loadA(5, 5);     // prefetch ring depth 6
#pragma unroll
      for (int i = 0; i < NKT; ++i) {
        const int sl = i % 6;
        const f16x8 a0 = Abuf[sl][0];
        const f16x8 a1 = Abuf[sl][1];
        if (i + 6 < NKT) loadA(i + 6, (i + 6) % 6);
        acc[0][0] = __builtin_amdgcn_mfma_f32_16x16x32_f16(a0, Wreg[0][i], acc[0][0], 0, 0, 0);
        acc[0][1] = __builtin_amdgcn_mfma_f32_16x16x32_f16(a0, Wreg[1][i], acc[0][1], 0, 0, 0);
        acc[1][0] = __builtin_amdgcn_mfma_f32_16x16x32_f16(a1, Wreg[0][i], acc[1][0], 0, 0, 0);
        acc[1][1] = __builtin_amdgcn_mfma_f32_16x16x32_f16(a1, Wreg[1][i], acc[1][1], 0, 0, 0);
      }

      // partial z -> LDS; region (nh*4 + kq) so stage-1 sums stride-1024 over kq
      float* zw = zbAll + (nh * 4 + kq) * 1024;
#pragma unroll
      for (int mt2 = 0; mt2 < 2; ++mt2)
#pragma unroll
        for (int nt = 0; nt < 2; ++nt)
#pragma unroll
          for (int e = 0; e < 4; ++e)
            zw[(mt2 * 2 + nt) * 256 + (quad * 4 + e) * 16 + c16] = acc[mt2][nt][e];

      __syncthreads();

      // stage 1: reduce 4 K-partials + bias, in place into kq=0 region
      {
        const int base = tid * 4;          // 512 thr x 4 = 2048 final z
        const int nh1  = base >> 10;
        const int off  = base & 1023;
        f32x4 s = (f32x4)0.0f;
#pragma unroll
        for (int q = 0; q < 4; ++q)
          s += *(const f32x4*)(zbAll + nh1 * 4096 + q * 1024 + off);
        const int nt1 = (off >> 8) & 1;
        const int c0  = off & 15;
        s += *(const f32x4*)(biasLDS + (nh1 * 2 + nt1) * 16 + c0);
        *(f32x4*)(zbAll + nh1 * 4096 + off) = s;
      }
      __syncthreads();

      // stage 2: fused gates; c stays in LDS; h published via write-through 4B stores
      {
        const int row = tid >> 4, u = tid & 15;
        const int mt2 = row >> 4, r16 = row & 15;
        const float z0 = zbAll[0 * 4096 + (mt2 * 2 + 0) * 256 + r16 * 16 + u];
        const float z1 = zbAll[0 * 4096 + (mt2 * 2 + 1) * 256 + r16 * 16 + u];
        const float z2 = zbAll[1 * 4096 + (mt2 * 2 + 0) * 256 + r16 * 16 + u];
        const float z3 = zbAll[1 * 4096 + (mt2 * 2 + 1) * 256 + r16 * 16 + u];
        const float cv = cLDS[tid];
        const float gt = tanh_(z0);
        const float iv = sigmoid_(z1);
        const float fv = sigmoid_(z2);
        const float ov = sigmoid_(z3);
        const float cn = gt * iv + cv * fv;
        cLDS[tid] = cn;
        const float hn = tanh_(cn) * ov;
        const float hn_hi = __shfl_down(hn, 1);
        if ((tid & 1) == 0)
          storeH2(hdst + (size_t)(rowbase + row) * H_ + ubase + u, hn, hn_hi);
      }
    }
    grid_barrier(sync, bid, p);
  }
}

__global__ __launch_bounds__(512, 2)
void lstm_persistent(const f16* __restrict__ x16,
                     const float* __restrict__ W0x, const float* __restrict__ W0h, const float* __restrict__ b0,
                     const float* __restrict__ W1x, const float* __restrict__ W1h, const float* __restrict__ b1,
                     f16* h0buf, f16* h1buf, unsigned* sync)
{
  __shared__ float zbAll[8192];    // 32KB: prologue panels / wave partial z / final z
  __shared__ float cLDS[512];
  __shared__ float biasLDS[64];
  const int bid = blockIdx.x;
  if (bid >= 128)
    role_main<true >(x16, W1x, W1h, b1, h0buf, h1buf, sync, bid, zbAll, cLDS, biasLDS);
  else
    role_main<false>(x16, W0x, W0h, b0, h0buf, h1buf, sync, bid, zbAll, cLDS, biasLDS);
}

// x fp32 -> f16, once
__global__ void cvt_x(const float* __restrict__ xin, f16* __restrict__ xo)
{
  const int i = (blockIdx.x * 256 + threadIdx.x) * 8;
  const float4 a = *(const float4*)(xin + i);
  const float4 b = *(const float4*)(xin + i + 4);
  f16x8 v;
  v[0] = (f16)a.x; v[1] = (f16)a.y; v[2] = (f16)a.z; v[3] = (f16)a.w;
  v[4] = (f16)b.x; v[5] = (f16)b.y; v[6] = (f16)b.z; v[7] = (f16)b.w;
  *(f16x8*)(xo + i) = v;
}

// out[b][c] = h1_final[b][:] . Wo[:][c] + bo[c]   (fp32 vector math)
__global__ void out_gemm(const f16* __restrict__ h1,
                         const float* __restrict__ Wo, const float* __restrict__ bo,
                         float* __restrict__ out)
{
  __shared__ float ht[1024][8];
  const int tid = threadIdx.x;    // 128 threads
  const int b0r = blockIdx.y * 4;
  for (int i = tid; i < 4096; i += 128) {
    const int rr = i >> 10, k = i & 1023;
    ht[k][rr] = (float)h1[(size_t)(b0r + rr) * H_ + k];
  }
  __syncthreads();
  const int c = blockIdx.x * 125 + tid;
  if (tid < 125) {
    float a0 = 0.f, a1 = 0.f, a2 = 0.f, a3 = 0.f;
#pragma unroll 4
    for (int k = 0; k < 1024; ++k) {
      const float w = Wo[(size_t)k * C_ + c];
      a0 += ht[k][0] * w;
      a1 += ht[k][1] * w;
      a2 += ht[k][2] * w;
      a3 += ht[k][3] * w;
    }
    const float bb = bo[c];
    out[(size_t)(b0r + 0) * C_ + c] = a0 + bb;
    out[(size_t)(b0r + 1) * C_ + c] = a1 + bb;
    out[(size_t)(b0r + 2) * C_ + c] = a2 + bb;
    out[(size_t)(b0r + 3) * C_ + c] = a3 + bb;
  }
}

extern "C" void kernel_launch(void* const* d_in, const int* in_sizes, int n_in,
                              void* d_out, int out_size, void* d_ws, size_t ws_size,
                              hipStream_t stream)
{
  const float* x   = (const float*)d_in[0];
  const float* W0x = (const float*)d_in[1];
  const float* W0h = (const float*)d_in[2];
  const float* b0  = (const float*)d_in[3];
  const float* W1x = (const float*)d_in[4];
  const float* W1h = (const float*)d_in[5];
  const float* b1  = (const float*)d_in[6];
  const float* Wo  = (const float*)d_in[7];
  const float* bo  = (const float*)d_in[8];

  unsigned* sync = (unsigned*)d_ws;                        // barrier counters (4KB)
  f16* h0buf = (f16*)((char*)d_ws + 4096);                 // [2][64][1024] f16
  f16* h1buf = h0buf + 2 * (B_ * H_);                      // [2][64][1024] f16
  f16* x16   = h1buf + 2 * (B_ * H_);                      // [64][256][256] f16 (8MB)

  hipMemsetAsync(d_ws, 0, 4096 + (size_t)4 * B_ * H_ * sizeof(f16), stream);

  hipLaunchKernelGGL(cvt_x, dim3((B_ * T_ * I_) / (256 * 8)), dim3(256), 0, stream, x, x16);

  hipLaunchKernelGGL(lstm_persistent, dim3(256), dim3(512), 0, stream,
                     x16, W0x, W0h, b0, W1x, W1h, b1, h0buf, h1buf, sync);

  // final h1 is at parity (T-1)&1 = 1
  hipLaunchKernelGGL(out_gemm, dim3(8, 16), dim3(128), 0, stream,
                     h1buf + (B_ * H_), Wo, bo, (float*)d_out);
}

// Round 3
// 3333.393 us; speedup vs baseline: 1.5798x; 1.5530x over previous
//
#include <hip/hip_runtime.h>
#include <cstddef>

#define B_  64
#define T_  256
#define I_  256
#define H_  1024
#define C_  1000

typedef _Float16 f16;
typedef __attribute__((ext_vector_type(8))) _Float16 f16x8;
typedef __attribute__((ext_vector_type(4))) float f32x4;

__device__ __forceinline__ float sigmoid_(float v) { return 1.0f / (1.0f + __expf(-v)); }
__device__ __forceinline__ float tanh_(float v) {
  float e = __expf(-2.0f * fabsf(v));
  float t = (1.0f - e) / (1.0f + e);
  return copysignf(t, v);
}

// h store: agent-scope relaxed atomic store -> write-through (no dirty L2 lines,
// so the barrier never needs a writeback; h never round-trips through HBM).
__device__ __forceinline__ void storeH2(f16* p, float a, float b) {
  union { f16 h[2]; unsigned u; } pk;
  pk.h[0] = (f16)a; pk.h[1] = (f16)b;
  __hip_atomic_store((unsigned*)p, pk.u, __ATOMIC_RELAXED, __HIP_MEMORY_SCOPE_AGENT);
}

// Two-level barrier, all RELAXED atomics. Release ordering comes free from
// __syncthreads (vmcnt(0) drains before s_barrier). Acquire side: ONE agent
// acquire fence (invalidate only — nothing dirty) so cached h loads refill.
__device__ __forceinline__ void grid_barrier(unsigned* sync, int bid, int phase) {
  __syncthreads();
  if (threadIdx.x == 0) {
    unsigned* master = sync;
    unsigned* bucket = sync + 32 * (1 + (bid & 7));   // 128B-spaced lines
    __hip_atomic_fetch_add(bucket, 1u, __ATOMIC_RELAXED, __HIP_MEMORY_SCOPE_AGENT);
    if (bid < 8) {
      const unsigned bt = 32u * (unsigned)(phase + 1);
      int g = 0;
      while (__hip_atomic_load(bucket, __ATOMIC_RELAXED, __HIP_MEMORY_SCOPE_AGENT) < bt) {
        __builtin_amdgcn_s_sleep(1);
        if (++g > (1 << 16)) break;
      }
      __hip_atomic_fetch_add(master, 1u, __ATOMIC_RELAXED, __HIP_MEMORY_SCOPE_AGENT);
    }
    const unsigned mt = 8u * (unsigned)(phase + 1);
    int g2 = 0;
    while (__hip_atomic_load(master, __ATOMIC_RELAXED, __HIP_MEMORY_SCOPE_AGENT) < mt) {
      __builtin_amdgcn_s_sleep(1);
      if (++g2 > (1 << 16)) break;
    }
    __builtin_amdgcn_fence(__ATOMIC_ACQUIRE, "agent");  // invalidate only
  }
  __syncthreads();
}

// One block = 512 threads = 8 waves = (K-split 4) x (N-split 2).
// Block tile: 32 batch rows x 64 gate-cols (4 gates x 16 units).
// Per-wave weights: (K/4) x 32 cols f16 = 128 VGPRs (L1) -> 2 waves/SIMD.
// CRITICAL: prologue loop must be FULLY unrolled so Wreg indexing is static
// (R2's `#pragma unroll 1` demoted Wreg to scratch -> 7 GB/launch re-fetch).
template<bool IS_L1>
__device__ __forceinline__ void role_main(
    const f16* __restrict__ x16,
    const float* __restrict__ Wx, const float* __restrict__ Wh,
    const float* __restrict__ bias,
    f16* __restrict__ h0buf, f16* __restrict__ h1buf,
    unsigned* sync, int bid,
    float* zbAll, float* cLDS, float* biasLDS)
{
  constexpr int KTOT = IS_L1 ? 64 : 40;   // k-tiles of 32 (L0: 8 x-tiles + 32 h-tiles)
  constexpr int NKT  = KTOT / 4;          // per-wave k-tiles (K-split over kq)
  constexpr int KX   = IS_L1 ? 1024 : 256;

  const int tid  = threadIdx.x;
  const int wv   = tid >> 6;          // 0..7
  const int nh   = wv >> 2;           // col-half (32 cols each)
  const int kq   = wv & 3;            // K quarter
  const int lane = tid & 63;
  const int c16  = lane & 15;
  const int quad = lane >> 4;
  const int rr7  = bid & 127;
  const int mgroup  = rr7 & 1;
  const int ubase   = (rr7 >> 1) * 16;
  const int rowbase = mgroup * 32;

  if (tid < 64) biasLDS[tid] = bias[(size_t)(tid >> 4) * H_ + ubase + (tid & 15)];
  if (tid < 512) cLDS[tid] = 0.0f;

  // ---- weight prologue: global fp32 -> per-wave LDS panel -> f16 B-frags in regs
  f16x8 Wreg[2][NKT];
  {
    f16* zpan = (f16*)zbAll + wv * 1024;   // private 2KB panel per wave
#pragma unroll
    for (int ii = 0; ii < NKT; ++ii) {
      const int kt = kq * NKT + ii;
#pragma unroll
      for (int rw = 0; rw < 16; ++rw) {
        const int krow  = rw * 2 + (lane >> 5);
        const int col32 = lane & 31;
        const int g = nh * 2 + (col32 >> 4);
        const int u = col32 & 15;
        const int k = kt * 32 + krow;
        float wval = (k < KX) ? Wx[((size_t)g * KX + k) * H_ + ubase + u]
                              : Wh[((size_t)g * H_ + (k - KX)) * H_ + ubase + u];
        zpan[krow * 32 + col32] = (f16)wval;
      }
#pragma unroll
      for (int nt = 0; nt < 2; ++nt) {
        f16x8 f;
#pragma unroll
        for (int j = 0; j < 8; ++j)
          f[j] = zpan[(quad * 8 + j) * 32 + nt * 16 + c16];  // B[n=lane&15][k=quad*8+j]
        Wreg[nt][ii] = f;
      }
    }
  }
  __syncthreads();

  const int ktbase = kq * NKT;
  const int row0 = rowbase + c16;

#pragma unroll 1
  for (int p = 0; p <= T_; ++p) {
    const bool active = IS_L1 ? (p >= 1) : (p < T_);
    if (active) {
      const f16* __restrict__ hA = h0buf + ((p + 1) & 1) * (B_ * H_);  // h0[p-1]
      const f16* __restrict__ hB = IS_L1 ? (h1buf + (p & 1) * (B_ * H_)) : (const f16*)nullptr;
      f16* __restrict__ hdst = IS_L1 ? (h1buf + ((p + 1) & 1) * (B_ * H_))
                                     : (h0buf + (p & 1) * (B_ * H_));

      f16x8 Abuf[4][2];
      auto loadA = [&](int ii, int slot) {
        const int kt = ktbase + ii;
        const int k  = kt * 32 + quad * 8;
#pragma unroll
        for (int mt2 = 0; mt2 < 2; ++mt2) {
          const int row = row0 + mt2 * 16;
          if (!IS_L1 && k < 256) {          // x-part: pre-converted f16, cached
            Abuf[slot][mt2] = *(const f16x8*)(x16 + ((size_t)row * T_ + p) * I_ + k);
          } else if (IS_L1 && k >= 1024) {
            Abuf[slot][mt2] = *(const f16x8*)(hB + (size_t)row * H_ + (k - 1024));
          } else {
            const int kk = IS_L1 ? k : (k - 256);
            Abuf[slot][mt2] = *(const f16x8*)(hA + (size_t)row * H_ + kk);
          }
        }
      };

      f32x4 acc[2][2];
#pragma unroll
      for (int mt2 = 0; mt2 < 2; ++mt2)
#pragma unroll
        for (int nt = 0; nt < 2; ++nt)
          acc[mt2][nt] = (f32x4)0.0f;

      loadA(0, 0); loadA(1, 1); loadA(2, 2); loadA(3, 3);  // prefetch ring depth 4
#pragma unroll
      for (int i = 0; i < NKT; ++i) {
        const int sl = i & 3;
        const f16x8 a0 = Abuf[sl][0];
        const f16x8 a1 = Abuf[sl][1];
        if (i + 4 < NKT) loadA(i + 4, (i + 4) & 3);
        acc[0][0] = __builtin_amdgcn_mfma_f32_16x16x32_f16(a0, Wreg[0][i], acc[0][0], 0, 0, 0);
        acc[0][1] = __builtin_amdgcn_mfma_f32_16x16x32_f16(a0, Wreg[1][i], acc[0][1], 0, 0, 0);
        acc[1][0] = __builtin_amdgcn_mfma_f32_16x16x32_f16(a1, Wreg[0][i], acc[1][0], 0, 0, 0);
        acc[1][1] = __builtin_amdgcn_mfma_f32_16x16x32_f16(a1, Wreg[1][i], acc[1][1], 0, 0, 0);
      }

      // partial z -> LDS; region (nh*4 + kq) so stage-1 sums stride-1024 over kq
      float* zw = zbAll + (nh * 4 + kq) * 1024;
#pragma unroll
      for (int mt2 = 0; mt2 < 2; ++mt2)
#pragma unroll
        for (int nt = 0; nt < 2; ++nt)
#pragma unroll
          for (int e = 0; e < 4; ++e)
            zw[(mt2 * 2 + nt) * 256 + (quad * 4 + e) * 16 + c16] = acc[mt2][nt][e];

      __syncthreads();

      // stage 1: reduce 4 K-partials + bias, in place into kq=0 region
      {
        const int base = tid * 4;          // 512 thr x 4 = 2048 final z
        const int nh1  = base >> 10;
        const int off  = base & 1023;
        f32x4 s = (f32x4)0.0f;
#pragma unroll
        for (int q = 0; q < 4; ++q)
          s += *(const f32x4*)(zbAll + nh1 * 4096 + q * 1024 + off);
        const int nt1 = (off >> 8) & 1;
        const int c0  = off & 15;
        s += *(const f32x4*)(biasLDS + (nh1 * 2 + nt1) * 16 + c0);
        *(f32x4*)(zbAll + nh1 * 4096 + off) = s;
      }
      __syncthreads();

      // stage 2: fused gates; c stays in LDS; h published via write-through 4B stores
      {
        const int row = tid >> 4, u = tid & 15;
        const int mt2 = row >> 4, r16 = row & 15;
        const float z0 = zbAll[0 * 4096 + (mt2 * 2 + 0) * 256 + r16 * 16 + u];
        const float z1 = zbAll[0 * 4096 + (mt2 * 2 + 1) * 256 + r16 * 16 + u];
        const float z2 = zbAll[1 * 4096 + (mt2 * 2 + 0) * 256 + r16 * 16 + u];
        const float z3 = zbAll[1 * 4096 + (mt2 * 2 + 1) * 256 + r16 * 16 + u];
        const float cv = cLDS[tid];
        const float gt = tanh_(z0);
        const float iv = sigmoid_(z1);
        const float fv = sigmoid_(z2);
        const float ov = sigmoid_(z3);
        const float cn = gt * iv + cv * fv;
        cLDS[tid] = cn;
        const float hn = tanh_(cn) * ov;
        const float hn_hi = __shfl_down(hn, 1);
        if ((tid & 1) == 0)
          storeH2(hdst + (size_t)(rowbase + row) * H_ + ubase + u, hn, hn_hi);
      }
    }
    grid_barrier(sync, bid, p);
  }
}

__global__ __launch_bounds__(512, 2)
void lstm_persistent(const f16* __restrict__ x16,
                     const float* __restrict__ W0x, const float* __restrict__ W0h, const float* __restrict__ b0,
                     const float* __restrict__ W1x, const float* __restrict__ W1h, const float* __restrict__ b1,
                     f16* h0buf, f16* h1buf, unsigned* sync)
{
  __shared__ float zbAll[8192];    // 32KB: prologue panels / wave partial z / final z
  __shared__ float cLDS[512];
  __shared__ float biasLDS[64];
  const int bid = blockIdx.x;
  if (bid >= 128)
    role_main<true >(x16, W1x, W1h, b1, h0buf, h1buf, sync, bid, zbAll, cLDS, biasLDS);
  else
    role_main<false>(x16, W0x, W0h, b0, h0buf, h1buf, sync, bid, zbAll, cLDS, biasLDS);
}

// x fp32 -> f16, once
__global__ void cvt_x(const float* __restrict__ xin, f16* __restrict__ xo)
{
  const int i = (blockIdx.x * 256 + threadIdx.x) * 8;
  const float4 a = *(const float4*)(xin + i);
  const float4 b = *(const float4*)(xin + i + 4);
  f16x8 v;
  v[0] = (f16)a.x; v[1] = (f16)a.y; v[2] = (f16)a.z; v[3] = (f16)a.w;
  v[4] = (f16)b.x; v[5] = (f16)b.y; v[6] = (f16)b.z; v[7] = (f16)b.w;
  *(f16x8*)(xo + i) = v;
}

// out[b][c] = h1_final[b][:] . Wo[:][c] + bo[c]   (fp32 vector math)
__global__ void out_gemm(const f16* __restrict__ h1,
                         const float* __restrict__ Wo, const float* __restrict__ bo,
                         float* __restrict__ out)
{
  __shared__ float ht[1024][8];
  const int tid = threadIdx.x;    // 128 threads
  const int b0r = blockIdx.y * 4;
  for (int i = tid; i < 4096; i += 128) {
    const int rr = i >> 10, k = i & 1023;
    ht[k][rr] = (float)h1[(size_t)(b0r + rr) * H_ + k];
  }
  __syncthreads();
  const int c = blockIdx.x * 125 + tid;
  if (tid < 125) {
    float a0 = 0.f, a1 = 0.f, a2 = 0.f, a3 = 0.f;
#pragma unroll 4
    for (int k = 0; k < 1024; ++k) {
      const float w = Wo[(size_t)k * C_ + c];
      a0 += ht[k][0] * w;
      a1 += ht[k][1] * w;
      a2 += ht[k][2] * w;
      a3 += ht[k][3] * w;
    }
    const float bb = bo[c];
    out[(size_t)(b0r + 0) * C_ + c] = a0 + bb;
    out[(size_t)(b0r + 1) * C_ + c] = a1 + bb;
    out[(size_t)(b0r + 2) * C_ + c] = a2 + bb;
    out[(size_t)(b0r + 3) * C_ + c] = a3 + bb;
  }
}

extern "C" void kernel_launch(void* const* d_in, const int* in_sizes, int n_in,
                              void* d_out, int out_size, void* d_ws, size_t ws_size,
                              hipStream_t stream)
{
  const float* x   = (const float*)d_in[0];
  const float* W0x = (const float*)d_in[1];
  const float* W0h = (const float*)d_in[2];
  const float* b0  = (const float*)d_in[3];
  const float* W1x = (const float*)d_in[4];
  const float* W1h = (const float*)d_in[5];
  const float* b1  = (const float*)d_in[6];
  const float* Wo  = (const float*)d_in[7];
  const float* bo  = (const float*)d_in[8];

  unsigned* sync = (unsigned*)d_ws;                        // barrier counters (4KB)
  f16* h0buf = (f16*)((char*)d_ws + 4096);                 // [2][64][1024] f16
  f16* h1buf = h0buf + 2 * (B_ * H_);                      // [2][64][1024] f16
  f16* x16   = h1buf + 2 * (B_ * H_);                      // [64][256][256] f16 (8MB)

  hipMemsetAsync(d_ws, 0, 4096 + (size_t)4 * B_ * H_ * sizeof(f16), stream);

  hipLaunchKernelGGL(cvt_x, dim3((B_ * T_ * I_) / (256 * 8)), dim3(256), 0, stream, x, x16);

  hipLaunchKernelGGL(lstm_persistent, dim3(256), dim3(512), 0, stream,
                     x16, W0x, W0h, b0, W1x, W1h, b1, h0buf, h1buf, sync);

  // final h1 is at parity (T-1)&1 = 1
  hipLaunchKernelGGL(out_gemm, dim3(8, 16), dim3(128), 0, stream,
                     h1buf + (B_ * H_), Wo, bo, (float*)d_out);
}